// Round 18
// baseline (421.070 us; speedup 1.0000x reference)
//
#include <hip/hip_runtime.h>
#include <hip/hip_bf16.h>
#include <math.h>

typedef __attribute__((ext_vector_type(8))) short short8;
typedef __attribute__((ext_vector_type(4))) float f32x4;
typedef __attribute__((ext_vector_type(2))) float f32x2;
typedef __attribute__((address_space(1))) const void gvoid;
typedef __attribute__((address_space(3))) void lvoid;

#define NC 8   // histogram privatization copies

__device__ __forceinline__ unsigned short f2bf(float f) {
    unsigned int u = __builtin_bit_cast(unsigned int, f);
    return (unsigned short)((u + 0x7fffu + ((u >> 16) & 1u)) >> 16);   // RNE
}
__device__ __forceinline__ float b2f(short s) {
    return __builtin_bit_cast(float, ((unsigned int)(unsigned short)s) << 16);
}
__device__ __forceinline__ unsigned int cvtpk(float lo, float hi) {
    unsigned int r;
    asm("v_cvt_pk_bf16_f32 %0, %1, %2" : "=v"(r) : "v"(lo), "v"(hi));
    return r;
}
// fp8 e4m3 (OCP) HW converts — word-select must be a LITERAL constant
__device__ __forceinline__ unsigned int pk8_lo(float a, float b, unsigned int old) {
    return (unsigned int)__builtin_amdgcn_cvt_pk_fp8_f32(a, b, (int)old, false);
}
__device__ __forceinline__ unsigned int pk8_hi(float a, float b, unsigned int old) {
    return (unsigned int)__builtin_amdgcn_cvt_pk_fp8_f32(a, b, (int)old, true);
}
__device__ __forceinline__ f32x2 up8_lo(unsigned int v) {
    return __builtin_amdgcn_cvt_pk_f32_fp8((int)v, false);
}
__device__ __forceinline__ f32x2 up8_hi(unsigned int v) {
    return __builtin_amdgcn_cvt_pk_f32_fp8((int)v, true);
}
// unpack 16 fp8 (uint4) and fma into 16-float accumulator
__device__ __forceinline__ void acc16(float* A, const uint4 u, const float n) {
    f32x2 p;
    p = up8_lo(u.x); A[0]  = fmaf(p.x, n, A[0]);  A[1]  = fmaf(p.y, n, A[1]);
    p = up8_hi(u.x); A[2]  = fmaf(p.x, n, A[2]);  A[3]  = fmaf(p.y, n, A[3]);
    p = up8_lo(u.y); A[4]  = fmaf(p.x, n, A[4]);  A[5]  = fmaf(p.y, n, A[5]);
    p = up8_hi(u.y); A[6]  = fmaf(p.x, n, A[6]);  A[7]  = fmaf(p.y, n, A[7]);
    p = up8_lo(u.z); A[8]  = fmaf(p.x, n, A[8]);  A[9]  = fmaf(p.y, n, A[9]);
    p = up8_hi(u.z); A[10] = fmaf(p.x, n, A[10]); A[11] = fmaf(p.y, n, A[11]);
    p = up8_lo(u.w); A[12] = fmaf(p.x, n, A[12]); A[13] = fmaf(p.y, n, A[13]);
    p = up8_hi(u.w); A[14] = fmaf(p.x, n, A[14]); A[15] = fmaf(p.y, n, A[15]);
}

// ============ FUSED: hist (privatized u64, rank) + weight pre-convert ============
__global__ __launch_bounds__(256) void hist_conv_kernel(
    const int* __restrict__ ei, const float* __restrict__ ea,
    unsigned long long* __restrict__ packed, int* __restrict__ rank, int N, int E,
    int eBlocks,
    const float* __restrict__ W1i, const float* __restrict__ W1r,
    const float* __restrict__ W2i, const float* __restrict__ W2r,
    unsigned short* __restrict__ W1t, unsigned short* __restrict__ W2t)
{
    if ((int)blockIdx.x < eBlocks) {
        int e = blockIdx.x * 256 + threadIdx.x;
        if (e >= E) return;
        const int copy = blockIdx.x & (NC - 1);
        int c = ei[(size_t)E + e];
        unsigned long long fx = (unsigned long long)(ea[e] * 1048576.0f + 0.5f);
        unsigned long long old = atomicAdd(&packed[(size_t)copy * N + c], (1ULL << 42) | fx);
        rank[e] = (int)(old >> 42);
    } else {
        int id = (blockIdx.x - eBlocks) * 256 + threadIdx.x;
        if (id < 256 * 768) {
            int n = id / 768, j = id % 768;
            int k = (j & ~63) | ((((j >> 3) & 7) ^ (n & 7)) << 3) | (j & 7);
            float v = (n < 128) ? W1i[k * 128 + n] : W1r[k * 128 + (n - 128)];
            W1t[id] = f2bf(v);
        } else {
            int id2 = id - 256 * 768;
            if (id2 < 128 * 256) {
                int n = id2 >> 8, j = id2 & 255;
                int k = (j & ~63) | ((((j >> 3) & 7) ^ (n & 7)) << 3) | (j & 7);
                float v = (k < 128) ? W2i[k * 128 + n] : W2r[(k - 128) * 128 + n];
                W2t[id2] = f2bf(v);
            }
        }
    }
}

// ============ scan pass 1: per-node total count over NC copies ============
__global__ __launch_bounds__(256) void scan1p_kernel(
    const unsigned long long* __restrict__ packed, int* __restrict__ out,
    int* __restrict__ blksum, int n)
{
    __shared__ int part[256];
    const int t = threadIdx.x;
    const int base = blockIdx.x * 1024 + t * 4;
    int v[4];
#pragma unroll
    for (int q = 0; q < 4; ++q) {
        int s = 0;
        if (base + q < n) {
#pragma unroll
            for (int p = 0; p < NC; ++p)
                s += (int)(packed[(size_t)p * n + base + q] >> 42);
        }
        v[q] = s;
    }
    const int s = v[0] + v[1] + v[2] + v[3];
    part[t] = s;
    __syncthreads();
    for (int off = 1; off < 256; off <<= 1) {
        int x = (t >= off) ? part[t - off] : 0;
        __syncthreads();
        part[t] += x;
        __syncthreads();
    }
    if (t == 255) blksum[blockIdx.x] = part[255];
    int run = part[t] - s;
#pragma unroll
    for (int q = 0; q < 4; ++q) {
        if (base + q < n) out[base + q] = run;
        run += v[q];
    }
}

// ============ finalize (re-scans <=256 block sums in shared): rowptr, wpb, dinv ============
__global__ __launch_bounds__(256) void scan3_kernel(
    int* __restrict__ rowptr, const int* __restrict__ blksum,
    int* __restrict__ wpb, const unsigned long long* __restrict__ packed,
    float* __restrict__ dinv, int n, int Etot, int nb)
{
    __shared__ int tmp[256];
    __shared__ int sexcl[256];
    const int t = threadIdx.x;
    const int v = (t < nb) ? blksum[t] : 0;
    tmp[t] = v;
    __syncthreads();
    for (int off = 1; off < 256; off <<= 1) {
        int x = (t >= off) ? tmp[t - off] : 0;
        __syncthreads();
        tmp[t] += x;
        __syncthreads();
    }
    sexcl[t] = tmp[t] - v;
    __syncthreads();
    const int i = blockIdx.x * 256 + t;
    if (i == 0) rowptr[n] = Etot;
    if (i >= n) return;
    int base = rowptr[i] + sexcl[i >> 10];
    rowptr[i] = base;
    unsigned long long degfx = 0;
    int acc = base;
#pragma unroll
    for (int p = 0; p < NC; ++p) {
        unsigned long long vv = packed[(size_t)p * n + i];
        wpb[(size_t)p * n + i] = acc;
        acc += (int)(vv >> 42);
        degfx += vv & ((1ULL << 42) - 1);
    }
    dinv[i] = (degfx > 0) ? rsqrtf((float)degfx * 9.5367431640625e-7f) : 0.f;
}

// ============ FUSED: MFMA dual GEMM (layer 1, WHOLE-K PANEL staging) + placement ============
// Tile M=32, K-panel staged ONCE: 16 thr/row stream 192B contiguous each ->
// full DRAM-row utilization; loop has ZERO A-traffic (only L2-hot B-DMA).
// LDS = 48KB (As[12] panel) + 32KB (Bs) = 80KB -> 2 blocks/CU.
__global__ __launch_bounds__(512) void gemm1_place_kernel(
    const float* __restrict__ A, const unsigned short* __restrict__ Wt,
    const float* __restrict__ bias, unsigned char* __restrict__ outP8,
    unsigned short* __restrict__ outR, int M, int K, int gB,
    const int* __restrict__ ei, const float* __restrict__ ea,
    const float* __restrict__ dinv, const int* __restrict__ wpb,
    const int* __restrict__ rank, int2* __restrict__ csr, int E)
{
    __shared__ __align__(16) unsigned char As[12][32 * 128];   // 48KB: 12 k-tiles x 32 rows
    __shared__ __align__(16) unsigned char Bs[256 * 128];      // 32KB

    if ((int)blockIdx.x >= gB) {
        // ---- placement branch: copy index MUST match hist's mapping (e>>8)&7 ----
        int e = (blockIdx.x - gB) * 512 + threadIdx.x;
        if (e >= E) return;
        const int copy = (e >> 8) & (NC - 1);
        int r = ei[e];
        int c = ei[(size_t)E + e];
        float nm = dinv[r] * ea[e] * dinv[c];
        int pos = wpb[(size_t)copy * M + c] + rank[e];
        int2 rec;
        rec.x = r;
        rec.y = __builtin_bit_cast(int, nm);
        csr[pos] = rec;
        return;
    }

    const int t = threadIdx.x;
    const int m0 = blockIdx.x * 32;
    const int lane = t & 63;
    const int wid = t >> 6;
    const int wm = wid >> 2;            // 0..1 : rows wm*16..wm*16+15
    const int wn = wid & 3;             // 0..3 : cols wn*64..wn*64+63
    const int lr = lane & 15;
    const int lk = (lane >> 4) * 8;

    f32x4 acc[4] = {};

    // ---- phase 1: stage whole A panel (row-contiguous reads) ----
    {
        const int pr  = t >> 4;          // row 0..31
        const int seg = t & 15;          // 16 segs/row, 48 floats (192B) each
        const int aRow = m0 + pr;
        const bool aOk = (aRow < M);
        const float* aSrc = A + (size_t)(aOk ? aRow : 0) * K + seg * 48;
        const int swz = (pr & 7) << 4;
#pragma unroll
        for (int j = 0; j < 6; ++j) {
            float4 f0 = {}, f1 = {};
            if (aOk) {
                f0 = *(const float4*)(aSrc + j * 8);
                f1 = *(const float4*)(aSrc + j * 8 + 4);
            }
            uint4 uv = {cvtpk(f0.x, f0.y), cvtpk(f0.z, f0.w),
                        cvtpk(f1.x, f1.y), cvtpk(f1.z, f1.w)};
            const int G = seg * 6 + j;         // global granule 0..95
            const int kt = G >> 3;
            const int g  = G & 7;
            *(uint4*)(&As[kt][pr * 128 + ((g * 16) ^ swz)]) = uv;
        }
    }
    // prologue: B-DMA tile 0
    const unsigned short* bSrc = Wt + (size_t)(lane >> 3) * K + (lane & 7) * 8;
#pragma unroll
    for (int i = 0; i < 4; ++i) {
        const int chunk = i * 8 + wid;
        __builtin_amdgcn_global_load_lds(
            (gvoid*)(bSrc + (size_t)chunk * 8 * K),
            (lvoid*)(Bs + chunk * 1024), 16, 0, 0);
    }

    for (int kt = 0; kt < 12; ++kt) {
        __syncthreads();   // B(kt) arrived; on kt==0 also panel writes visible
#pragma unroll
        for (int ks = 0; ks < 2; ++ks) {
            short8 a, b[4];
            {
                const int r = wm * 16 + lr;
                a = *(const short8*)(&As[kt][r * 128 + (((ks * 32 + lk) * 2) ^ ((r & 7) << 4))]);
            }
#pragma unroll
            for (int nf = 0; nf < 4; ++nf) {
                const int n = wn * 64 + nf * 16 + lr;
                b[nf] = *(const short8*)(Bs + n * 128 + (((ks * 32 + lk) * 2) ^ ((n & 7) << 4)));
            }
#pragma unroll
            for (int nf = 0; nf < 4; ++nf)
                acc[nf] = __builtin_amdgcn_mfma_f32_16x16x32_bf16(a, b[nf], acc[nf], 0, 0, 0);
        }
        __syncthreads();   // Bs free
        if (kt + 1 < 12) {
            const int k1 = (kt + 1) * 64;
#pragma unroll
            for (int i = 0; i < 4; ++i) {
                const int chunk = i * 8 + wid;
                __builtin_amdgcn_global_load_lds(
                    (gvoid*)(bSrc + (size_t)chunk * 8 * K + k1),
                    (lvoid*)(Bs + chunk * 1024), 16, 0, 0);
            }
        }
    }

#pragma unroll
    for (int nf = 0; nf < 4; ++nf) {
        const int n = wn * 64 + nf * 16 + lr;
        const f32x4 v = acc[nf];
        const int mb = m0 + wm * 16 + (lane >> 4) * 4;
        if (n < 128) {
            const unsigned int u01 = pk8_lo(v[0], v[1], 0u);
            const unsigned int u23 = pk8_lo(v[2], v[3], 0u);
            if (mb + 0 < M) outP8[(size_t)(mb + 0) * 128 + n] = (unsigned char)(u01);
            if (mb + 1 < M) outP8[(size_t)(mb + 1) * 128 + n] = (unsigned char)(u01 >> 8);
            if (mb + 2 < M) outP8[(size_t)(mb + 2) * 128 + n] = (unsigned char)(u23);
            if (mb + 3 < M) outP8[(size_t)(mb + 3) * 128 + n] = (unsigned char)(u23 >> 8);
        } else {
            const int nl = n - 128;
            const float badd = bias[nl];
#pragma unroll
            for (int j = 0; j < 4; ++j) {
                if (mb + j < M) outR[(size_t)(mb + j) * 128 + nl] = f2bf(v[j] + badd);
            }
        }
    }
}

// ============ MFMA single GEMM (layer 2, K=256 over bf16 [ah|h]) + bias + ReLU ============
__global__ __launch_bounds__(512) void gemm_mfma_single(
    const unsigned short* __restrict__ Aa,   // ah bf16 : k in [0,128)
    const unsigned short* __restrict__ Ah,   // h  bf16 : k in [128,256)
    const unsigned short* __restrict__ Wt,   // 128 x 256 bf16 pre-swizzled
    const float* __restrict__ bias,
    unsigned short* __restrict__ outX, int M)
{
    __shared__ __align__(16) unsigned char As[128 * 128];
    __shared__ __align__(16) unsigned char Bs[128 * 128];

    const int t = threadIdx.x;
    const int m0 = blockIdx.x * 128;
    const int lane = t & 63;
    const int wid = t >> 6;
    const int wm = wid >> 1;
    const int wn = wid & 1;
    const int lr = lane & 15;
    const int lk = (lane >> 4) * 8;

    f32x4 acc[2][4] = {};

    const int sr = t >> 2;
    const int sk = (t & 3) * 16;
    const int aRow = m0 + sr;
    const bool aOk = (aRow < M);
    const int rowSafe = aOk ? aRow : 0;
    const int sw = (sr & 7) << 4;
    const unsigned short* bSrc = Wt + (size_t)(lane >> 3) * 256 + (lane & 7) * 8;

    for (int k0 = 0; k0 < 256; k0 += 64) {
#pragma unroll
        for (int i = 0; i < 2; ++i) {
            const int chunk = i * 8 + wid;
            __builtin_amdgcn_global_load_lds(
                (gvoid*)(bSrc + (size_t)chunk * 8 * 256 + k0),
                (lvoid*)(Bs + chunk * 1024), 16, 0, 0);
        }
        const unsigned short* src =
            (k0 < 128 ? Aa : Ah) + (size_t)rowSafe * 128 + (k0 & 127) + sk;
        const short8 v0 = *(const short8*)(src);
        const short8 v1 = *(const short8*)(src + 8);
        *(short8*)(As + sr * 128 + ((sk * 2) ^ sw)) = v0;
        *(short8*)(As + sr * 128 + ((sk * 2 + 16) ^ sw)) = v1;
        __syncthreads();
#pragma unroll
        for (int ks = 0; ks < 2; ++ks) {
            short8 a[2], b[4];
#pragma unroll
            for (int mf = 0; mf < 2; ++mf) {
                const int r = wm * 32 + mf * 16 + lr;
                a[mf] = *(const short8*)(As + r * 128 + (((ks * 32 + lk) * 2) ^ ((r & 7) << 4)));
            }
#pragma unroll
            for (int nf = 0; nf < 4; ++nf) {
                const int n = wn * 64 + nf * 16 + lr;
                b[nf] = *(const short8*)(Bs + n * 128 + (((ks * 32 + lk) * 2) ^ ((n & 7) << 4)));
            }
#pragma unroll
            for (int mf = 0; mf < 2; ++mf)
#pragma unroll
                for (int nf = 0; nf < 4; ++nf)
                    acc[mf][nf] = __builtin_amdgcn_mfma_f32_16x16x32_bf16(
                        a[mf], b[nf], acc[mf][nf], 0, 0, 0);
        }
        __syncthreads();
    }

#pragma unroll
    for (int mf = 0; mf < 2; ++mf) {
#pragma unroll
        for (int nf = 0; nf < 4; ++nf) {
            const int n = wn * 64 + nf * 16 + lr;
            const float bb = bias[n];
            const f32x4 v = acc[mf][nf];
#pragma unroll
            for (int j = 0; j < 4; ++j) {
                const int m = m0 + wm * 32 + mf * 16 + (lane >> 4) * 4 + j;
                if (m < M) outX[(size_t)m * 128 + n] = f2bf(fmaxf(v[j] + bb, 0.f));
            }
        }
    }
}

// ============ agg1: gather fp8 P -> h (bf16 + fp8); 8 lanes/node, uint4 loads ============
__global__ __launch_bounds__(256) void agg_bias_relu(
    const unsigned char* __restrict__ P8, const unsigned short* __restrict__ Rbf,
    const int* __restrict__ rowptr, const int2* __restrict__ csr,
    unsigned short* __restrict__ hout, unsigned char* __restrict__ h8out, int N)
{
    const int i = blockIdx.x * 32 + (threadIdx.x >> 3);
    const int l = threadIdx.x & 7;
    if (i >= N) return;
    const int beg = rowptr[i];
    const int end = rowptr[i + 1];
    const int c = l * 16;

    float A0[16] = {}, A1[16] = {};
    int j = beg;
    for (; j + 1 < end; j += 2) {
        const int2 e0 = csr[j], e1 = csr[j + 1];
        const uint4 u0 = *(const uint4*)(P8 + (size_t)e0.x * 128 + c);
        const uint4 u1 = *(const uint4*)(P8 + (size_t)e1.x * 128 + c);
        acc16(A0, u0, __builtin_bit_cast(float, e0.y));
        acc16(A1, u1, __builtin_bit_cast(float, e1.y));
    }
    if (j < end) {
        const int2 e0 = csr[j];
        const uint4 u0 = *(const uint4*)(P8 + (size_t)e0.x * 128 + c);
        acc16(A0, u0, __builtin_bit_cast(float, e0.y));
    }
    const short8 r0 = *(const short8*)(Rbf + (size_t)i * 128 + c);
    const short8 r1 = *(const short8*)(Rbf + (size_t)i * 128 + c + 8);
    float s[16];
    short8 o0, o1;
#pragma unroll
    for (int q = 0; q < 8; ++q) {
        s[q] = fmaxf(A0[q] + A1[q] + b2f(r0[q]), 0.f);
        o0[q] = (short)f2bf(s[q]);
    }
#pragma unroll
    for (int q = 8; q < 16; ++q) {
        s[q] = fmaxf(A0[q] + A1[q] + b2f(r1[q - 8]), 0.f);
        o1[q - 8] = (short)f2bf(s[q]);
    }
    *(short8*)(hout + (size_t)i * 128 + c) = o0;
    *(short8*)(hout + (size_t)i * 128 + c + 8) = o1;
    uint4 w;
    w.x = pk8_hi(s[2],  s[3],  pk8_lo(s[0],  s[1],  0u));
    w.y = pk8_hi(s[6],  s[7],  pk8_lo(s[4],  s[5],  0u));
    w.z = pk8_hi(s[10], s[11], pk8_lo(s[8],  s[9],  0u));
    w.w = pk8_hi(s[14], s[15], pk8_lo(s[12], s[13], 0u));
    *(uint4*)(h8out + (size_t)i * 128 + c) = w;
}

// ============ agg2: ah = bf16(gather(fp8 h)); 8 lanes/node, uint4 loads ============
__global__ __launch_bounds__(256) void agg_plain(
    const unsigned char* __restrict__ H8,
    const int* __restrict__ rowptr, const int2* __restrict__ csr,
    unsigned short* __restrict__ ahout, int N)
{
    const int i = blockIdx.x * 32 + (threadIdx.x >> 3);
    const int l = threadIdx.x & 7;
    if (i >= N) return;
    const int beg = rowptr[i];
    const int end = rowptr[i + 1];
    const int c = l * 16;

    float A0[16] = {}, A1[16] = {};
    int j = beg;
    for (; j + 1 < end; j += 2) {
        const int2 e0 = csr[j], e1 = csr[j + 1];
        const uint4 u0 = *(const uint4*)(H8 + (size_t)e0.x * 128 + c);
        const uint4 u1 = *(const uint4*)(H8 + (size_t)e1.x * 128 + c);
        acc16(A0, u0, __builtin_bit_cast(float, e0.y));
        acc16(A1, u1, __builtin_bit_cast(float, e1.y));
    }
    if (j < end) {
        const int2 e0 = csr[j];
        const uint4 u0 = *(const uint4*)(H8 + (size_t)e0.x * 128 + c);
        acc16(A0, u0, __builtin_bit_cast(float, e0.y));
    }
    short8 o0, o1;
#pragma unroll
    for (int q = 0; q < 8; ++q)  o0[q] = (short)f2bf(A0[q] + A1[q]);
#pragma unroll
    for (int q = 8; q < 16; ++q) o1[q - 8] = (short)f2bf(A0[q] + A1[q]);
    *(short8*)(ahout + (size_t)i * 128 + c) = o0;
    *(short8*)(ahout + (size_t)i * 128 + c + 8) = o1;
}

// ============ fused mean-pool (sorted batch, bf16, 4 node-streams) + MLP ============
__global__ __launch_bounds__(256) void pool_mlp(
    const unsigned short* __restrict__ nx, const int* __restrict__ batch, int N,
    const float* __restrict__ Wl1, const float* __restrict__ bl1,
    const float* __restrict__ Wl2, const float* __restrict__ bl2,
    float* __restrict__ out)
{
    __shared__ float gxp[4][128];
    __shared__ float hid[32];
    __shared__ int rng[2];
    const int g = blockIdx.x;
    const int t = threadIdx.x;
    if (t < 2) {
        const int target = g + t;
        int lo = 0, hi = N;
        while (lo < hi) {
            int mid = (lo + hi) >> 1;
            if (batch[mid] < target) lo = mid + 1; else hi = mid;
        }
        rng[t] = lo;
    }
    __syncthreads();
    const int s = rng[0], e = rng[1];
    const int pr = t & 63;
    const int strm = t >> 6;
    float a0 = 0.f, b0 = 0.f, a1 = 0.f, b1 = 0.f;
    int i = s + strm;
    for (; i + 4 < e; i += 8) {
        const unsigned int u = *(const unsigned int*)&nx[(size_t)i * 128 + pr * 2];
        const unsigned int v = *(const unsigned int*)&nx[(size_t)(i + 4) * 128 + pr * 2];
        a0 += b2f((short)(u & 0xffff)); b0 += b2f((short)(u >> 16));
        a1 += b2f((short)(v & 0xffff)); b1 += b2f((short)(v >> 16));
    }
    if (i < e) {
        const unsigned int u = *(const unsigned int*)&nx[(size_t)i * 128 + pr * 2];
        a0 += b2f((short)(u & 0xffff)); b0 += b2f((short)(u >> 16));
    }
    gxp[strm][pr * 2] = a0 + a1;
    gxp[strm][pr * 2 + 1] = b0 + b1;
    __syncthreads();
    if (t < 128) {
        gxp[0][t] = ((gxp[0][t] + gxp[1][t]) + (gxp[2][t] + gxp[3][t]))
                    / fmaxf((float)(e - s), 1.f);
    }
    __syncthreads();
    if (t < 32) {
        float a = bl1[t];
#pragma unroll 8
        for (int k = 0; k < 128; ++k) a = fmaf(gxp[0][k], Wl1[k * 32 + t], a);
        hid[t] = a > 0.f ? a : expm1f(a);
    }
    __syncthreads();
    if (t < 2) {
        float a = bl2[t];
#pragma unroll
        for (int k = 0; k < 32; ++k) a = fmaf(hid[k], Wl2[k * 2 + t], a);
        out[(size_t)g * 2 + t] = a;
    }
}

extern "C" void kernel_launch(void* const* d_in, const int* in_sizes, int n_in,
                              void* d_out, int out_size, void* d_ws, size_t ws_size,
                              hipStream_t stream)
{
    const float* x     = (const float*)d_in[0];
    const int*   ei    = (const int*)d_in[1];
    const float* ea    = (const float*)d_in[2];
    const int*   batch = (const int*)d_in[3];
    const float* W1i   = (const float*)d_in[5];
    const float* W1r   = (const float*)d_in[6];
    const float* b1    = (const float*)d_in[7];
    const float* W2i   = (const float*)d_in[8];
    const float* W2r   = (const float*)d_in[9];
    const float* b2    = (const float*)d_in[10];
    const float* Wl1   = (const float*)d_in[11];
    const float* bl1   = (const float*)d_in[12];
    const float* Wl2   = (const float*)d_in[13];
    const float* bl2   = (const float*)d_in[14];

    const int N = in_sizes[0] / 768;
    const int E = in_sizes[2];
    const int G = out_size / 2;

    char* ws = (char*)d_ws;
    size_t off = 0;
    auto alloc = [&](size_t bytes) -> char* {
        char* p = ws + off;
        off = (off + bytes + 255) & ~(size_t)255;
        return p;
    };
    unsigned long long* packed = (unsigned long long*)alloc((size_t)NC * N * 8);
    int*   rank    = (int*)alloc((size_t)E * 4);
    int*   wpb     = (int*)alloc((size_t)NC * N * 4);
    float* dinv    = (float*)alloc((size_t)N * 4);
    int*   rowptr  = (int*)alloc((size_t)(N + 1) * 4);
    int*   blksum  = (int*)alloc((size_t)256 * 4);
    int2*  csr     = (int2*)alloc((size_t)E * 8);
    unsigned char*  P8   = (unsigned char*)alloc((size_t)N * 128);
    unsigned char*  H8   = (unsigned char*)alloc((size_t)N * 128);
    unsigned short* R1   = (unsigned short*)alloc((size_t)N * 128 * 2);
    unsigned short* hbf  = (unsigned short*)alloc((size_t)N * 128 * 2);
    unsigned short* ahb  = (unsigned short*)alloc((size_t)N * 128 * 2);
    unsigned short* nxb  = (unsigned short*)alloc((size_t)N * 128 * 2);
    unsigned short* W1t  = (unsigned short*)alloc((size_t)256 * 768 * 2);
    unsigned short* W2t  = (unsigned short*)alloc((size_t)128 * 256 * 2);

    const int eBlocks = (E + 255) / 256;
    const int cBlocks = (256 * 768 + 128 * 256 + 255) / 256;
    const int nb      = (N + 1023) / 1024;     // <=256 assumed
    const int nBlocks = (N + 255) / 256;
    const int aBlocks = (N + 31) / 32;
    const int gB      = (N + 31) / 32;         // M=32 tiles
    const int pB      = (E + 511) / 512;

    // ---- CSR build (phases 1-3) + weight convert ----
    (void)hipMemsetAsync(packed, 0, (size_t)NC * N * 8, stream);
    hist_conv_kernel<<<eBlocks + cBlocks, 256, 0, stream>>>(
        ei, ea, packed, rank, N, E, eBlocks, W1i, W1r, W2i, W2r, W1t, W2t);
    scan1p_kernel<<<nb, 256, 0, stream>>>(packed, rowptr, blksum, N);
    scan3_kernel<<<nBlocks, 256, 0, stream>>>(rowptr, blksum, wpb, packed, dinv, N, E, nb);

    // ---- layer 1 GEMM (whole-K panel) + edge placement (fused) ----
    gemm1_place_kernel<<<gB + pB, 512, 0, stream>>>(
        x, W1t, b1, P8, R1, N, 768, gB, ei, ea, dinv, wpb, rank, csr, E);

    // ---- h = relu(R1 + gather(P8)) -> hbf (bf16) + H8 (fp8) ----
    agg_bias_relu<<<aBlocks, 256, 0, stream>>>(P8, R1, rowptr, csr, hbf, H8, N);

    // ---- layer 2: ah = bf16(gather(H8)); node_x = bf16(relu([ah|h]@W2 + b2)) ----
    agg_plain<<<aBlocks, 256, 0, stream>>>(H8, rowptr, csr, ahb, N);
    gemm_mfma_single<<<(N + 127) / 128, 512, 0, stream>>>(ahb, hbf, W2t, b2, nxb, N);

    // ---- fused pool + head ----
    pool_mlp<<<G, 256, 0, stream>>>(nxb, batch, N, Wl1, bl1, Wl2, bl2, (float*)d_out);
}

// Round 19
// 369.713 us; speedup vs baseline: 1.1389x; 1.1389x over previous
//
#include <hip/hip_runtime.h>
#include <hip/hip_bf16.h>
#include <math.h>

typedef __attribute__((ext_vector_type(8))) short short8;
typedef __attribute__((ext_vector_type(4))) float f32x4;
typedef __attribute__((ext_vector_type(2))) float f32x2;
typedef __attribute__((address_space(1))) const void gvoid;
typedef __attribute__((address_space(3))) void lvoid;

#define NC 8   // histogram privatization copies

__device__ __forceinline__ unsigned short f2bf(float f) {
    unsigned int u = __builtin_bit_cast(unsigned int, f);
    return (unsigned short)((u + 0x7fffu + ((u >> 16) & 1u)) >> 16);   // RNE
}
__device__ __forceinline__ float b2f(short s) {
    return __builtin_bit_cast(float, ((unsigned int)(unsigned short)s) << 16);
}
__device__ __forceinline__ unsigned int cvtpk(float lo, float hi) {
    unsigned int r;
    asm("v_cvt_pk_bf16_f32 %0, %1, %2" : "=v"(r) : "v"(lo), "v"(hi));
    return r;
}
// fp8 e4m3 (OCP) HW converts — word-select must be a LITERAL constant
__device__ __forceinline__ unsigned int pk8_lo(float a, float b, unsigned int old) {
    return (unsigned int)__builtin_amdgcn_cvt_pk_fp8_f32(a, b, (int)old, false);
}
__device__ __forceinline__ unsigned int pk8_hi(float a, float b, unsigned int old) {
    return (unsigned int)__builtin_amdgcn_cvt_pk_fp8_f32(a, b, (int)old, true);
}
__device__ __forceinline__ f32x2 up8_lo(unsigned int v) {
    return __builtin_amdgcn_cvt_pk_f32_fp8((int)v, false);
}
__device__ __forceinline__ f32x2 up8_hi(unsigned int v) {
    return __builtin_amdgcn_cvt_pk_f32_fp8((int)v, true);
}

// ============ FUSED: hist (privatized u64, rank) + weight pre-convert ============
__global__ __launch_bounds__(256) void hist_conv_kernel(
    const int* __restrict__ ei, const float* __restrict__ ea,
    unsigned long long* __restrict__ packed, int* __restrict__ rank, int N, int E,
    int eBlocks,
    const float* __restrict__ W1i, const float* __restrict__ W1r,
    const float* __restrict__ W2i, const float* __restrict__ W2r,
    unsigned short* __restrict__ W1t, unsigned short* __restrict__ W2t)
{
    if ((int)blockIdx.x < eBlocks) {
        int e = blockIdx.x * 256 + threadIdx.x;
        if (e >= E) return;
        const int copy = blockIdx.x & (NC - 1);
        int c = ei[(size_t)E + e];
        unsigned long long fx = (unsigned long long)(ea[e] * 1048576.0f + 0.5f);
        unsigned long long old = atomicAdd(&packed[(size_t)copy * N + c], (1ULL << 42) | fx);
        rank[e] = (int)(old >> 42);
    } else {
        int id = (blockIdx.x - eBlocks) * 256 + threadIdx.x;
        if (id < 256 * 768) {
            int n = id / 768, j = id % 768;
            int k = (j & ~63) | ((((j >> 3) & 7) ^ (n & 7)) << 3) | (j & 7);
            float v = (n < 128) ? W1i[k * 128 + n] : W1r[k * 128 + (n - 128)];
            W1t[id] = f2bf(v);
        } else {
            int id2 = id - 256 * 768;
            if (id2 < 128 * 256) {
                int n = id2 >> 8, j = id2 & 255;
                int k = (j & ~63) | ((((j >> 3) & 7) ^ (n & 7)) << 3) | (j & 7);
                float v = (k < 128) ? W2i[k * 128 + n] : W2r[(k - 128) * 128 + n];
                W2t[id2] = f2bf(v);
            }
        }
    }
}

// ============ scan pass 1: per-node total count over NC copies ============
__global__ __launch_bounds__(256) void scan1p_kernel(
    const unsigned long long* __restrict__ packed, int* __restrict__ out,
    int* __restrict__ blksum, int n)
{
    __shared__ int part[256];
    const int t = threadIdx.x;
    const int base = blockIdx.x * 1024 + t * 4;
    int v[4];
#pragma unroll
    for (int q = 0; q < 4; ++q) {
        int s = 0;
        if (base + q < n) {
#pragma unroll
            for (int p = 0; p < NC; ++p)
                s += (int)(packed[(size_t)p * n + base + q] >> 42);
        }
        v[q] = s;
    }
    const int s = v[0] + v[1] + v[2] + v[3];
    part[t] = s;
    __syncthreads();
    for (int off = 1; off < 256; off <<= 1) {
        int x = (t >= off) ? part[t - off] : 0;
        __syncthreads();
        part[t] += x;
        __syncthreads();
    }
    if (t == 255) blksum[blockIdx.x] = part[255];
    int run = part[t] - s;
#pragma unroll
    for (int q = 0; q < 4; ++q) {
        if (base + q < n) out[base + q] = run;
        run += v[q];
    }
}

// ============ finalize (re-scans <=256 block sums in shared): rowptr, wpb, dinv ============
__global__ __launch_bounds__(256) void scan3_kernel(
    int* __restrict__ rowptr, const int* __restrict__ blksum,
    int* __restrict__ wpb, const unsigned long long* __restrict__ packed,
    float* __restrict__ dinv, int n, int Etot, int nb)
{
    __shared__ int tmp[256];
    __shared__ int sexcl[256];
    const int t = threadIdx.x;
    const int v = (t < nb) ? blksum[t] : 0;
    tmp[t] = v;
    __syncthreads();
    for (int off = 1; off < 256; off <<= 1) {
        int x = (t >= off) ? tmp[t - off] : 0;
        __syncthreads();
        tmp[t] += x;
        __syncthreads();
    }
    sexcl[t] = tmp[t] - v;
    __syncthreads();
    const int i = blockIdx.x * 256 + t;
    if (i == 0) rowptr[n] = Etot;
    if (i >= n) return;
    int base = rowptr[i] + sexcl[i >> 10];
    rowptr[i] = base;
    unsigned long long degfx = 0;
    int acc = base;
#pragma unroll
    for (int p = 0; p < NC; ++p) {
        unsigned long long vv = packed[(size_t)p * n + i];
        wpb[(size_t)p * n + i] = acc;
        acc += (int)(vv >> 42);
        degfx += vv & ((1ULL << 42) - 1);
    }
    dinv[i] = (degfx > 0) ? rsqrtf((float)degfx * 9.5367431640625e-7f) : 0.f;
}

// ============ edge placement: NO atomics (base + rank) ============
__global__ __launch_bounds__(256) void place_kernel(
    const int* __restrict__ ei, const float* __restrict__ ea,
    const float* __restrict__ dinv, const int* __restrict__ wpb,
    const int* __restrict__ rank, int2* __restrict__ csr, int N, int E)
{
    int e = blockIdx.x * 256 + threadIdx.x;
    if (e >= E) return;
    const int copy = blockIdx.x & (NC - 1);
    int r = ei[e];
    int c = ei[(size_t)E + e];
    float nm = dinv[r] * ea[e] * dinv[c];
    int pos = wpb[(size_t)copy * N + c] + rank[e];
    int2 rec;
    rec.x = r;
    rec.y = __builtin_bit_cast(int, nm);
    csr[pos] = rec;
}

// ============ MFMA dual GEMM (layer 1), single-buffered ============
// outP: fp8 e4m3 (gather operand only); outR: bf16.
__global__ __launch_bounds__(512) void gemm_mfma_dual(
    const float* __restrict__ A, const unsigned short* __restrict__ Wt,
    const float* __restrict__ bias, unsigned char* __restrict__ outP8,
    unsigned short* __restrict__ outR, int M, int K)
{
    __shared__ __align__(16) unsigned char As[64 * 128];
    __shared__ __align__(16) unsigned char Bs[256 * 128];

    const int t = threadIdx.x;
    const int m0 = blockIdx.x * 64;
    const int lane = t & 63;
    const int wid = t >> 6;
    const int wm = wid >> 2;
    const int wn = wid & 3;
    const int lr = lane & 15;
    const int lk = (lane >> 4) * 8;

    f32x4 acc[2][4] = {};

    const int sr = t >> 3;
    const int sk = (t & 7) * 8;
    const int aRow = m0 + sr;
    const bool aOk = (aRow < M);
    const float* aSrc = A + (size_t)(aOk ? aRow : 0) * K + sk;
    const int aDst = sr * 128 + ((sk * 2) ^ ((sr & 7) << 4));
    const unsigned short* bSrc = Wt + (size_t)(lane >> 3) * K + (lane & 7) * 8;

    for (int k0 = 0; k0 < K; k0 += 64) {
#pragma unroll
        for (int i = 0; i < 4; ++i) {
            const int chunk = i * 8 + wid;
            __builtin_amdgcn_global_load_lds(
                (gvoid*)(bSrc + (size_t)chunk * 8 * K + k0),
                (lvoid*)(Bs + chunk * 1024), 16, 0, 0);
        }
        unsigned int p0 = 0, p1 = 0, p2 = 0, p3 = 0;
        if (aOk) {
            const float4 f0 = *(const float4*)(aSrc + k0);
            const float4 f1 = *(const float4*)(aSrc + k0 + 4);
            p0 = cvtpk(f0.x, f0.y);
            p1 = cvtpk(f0.z, f0.w);
            p2 = cvtpk(f1.x, f1.y);
            p3 = cvtpk(f1.z, f1.w);
        }
        uint4 uv = {p0, p1, p2, p3};
        *(uint4*)(As + aDst) = uv;
        __syncthreads();
#pragma unroll
        for (int ks = 0; ks < 2; ++ks) {
            short8 a[2], b[4];
#pragma unroll
            for (int mf = 0; mf < 2; ++mf) {
                const int r = wm * 32 + mf * 16 + lr;
                a[mf] = *(const short8*)(As + r * 128 + (((ks * 32 + lk) * 2) ^ ((r & 7) << 4)));
            }
#pragma unroll
            for (int nf = 0; nf < 4; ++nf) {
                const int n = wn * 64 + nf * 16 + lr;
                b[nf] = *(const short8*)(Bs + n * 128 + (((ks * 32 + lk) * 2) ^ ((n & 7) << 4)));
            }
#pragma unroll
            for (int mf = 0; mf < 2; ++mf)
#pragma unroll
                for (int nf = 0; nf < 4; ++nf)
                    acc[mf][nf] = __builtin_amdgcn_mfma_f32_16x16x32_bf16(
                        a[mf], b[nf], acc[mf][nf], 0, 0, 0);
        }
        __syncthreads();
    }

#pragma unroll
    for (int mf = 0; mf < 2; ++mf) {
#pragma unroll
        for (int nf = 0; nf < 4; ++nf) {
            const int n = wn * 64 + nf * 16 + lr;
            const f32x4 v = acc[mf][nf];
            const int mb = m0 + wm * 32 + mf * 16 + (lane >> 4) * 4;
            if (n < 128) {
                const unsigned int u01 = pk8_lo(v[0], v[1], 0u);
                const unsigned int u23 = pk8_lo(v[2], v[3], 0u);
                if (mb + 0 < M) outP8[(size_t)(mb + 0) * 128 + n] = (unsigned char)(u01);
                if (mb + 1 < M) outP8[(size_t)(mb + 1) * 128 + n] = (unsigned char)(u01 >> 8);
                if (mb + 2 < M) outP8[(size_t)(mb + 2) * 128 + n] = (unsigned char)(u23);
                if (mb + 3 < M) outP8[(size_t)(mb + 3) * 128 + n] = (unsigned char)(u23 >> 8);
            } else {
                const int nl = n - 128;
                const float badd = bias[nl];
#pragma unroll
                for (int j = 0; j < 4; ++j) {
                    if (mb + j < M) outR[(size_t)(mb + j) * 128 + nl] = f2bf(v[j] + badd);
                }
            }
        }
    }
}

// ============ MFMA single GEMM (layer 2, K=256 over bf16 [ah|h]) + bias + ReLU ============
__global__ __launch_bounds__(512) void gemm_mfma_single(
    const unsigned short* __restrict__ Aa,   // ah bf16 : k in [0,128)
    const unsigned short* __restrict__ Ah,   // h  bf16 : k in [128,256)
    const unsigned short* __restrict__ Wt,   // 128 x 256 bf16 pre-swizzled
    const float* __restrict__ bias,
    unsigned short* __restrict__ outX, int M)
{
    __shared__ __align__(16) unsigned char As[128 * 128];
    __shared__ __align__(16) unsigned char Bs[128 * 128];

    const int t = threadIdx.x;
    const int m0 = blockIdx.x * 128;
    const int lane = t & 63;
    const int wid = t >> 6;
    const int wm = wid >> 1;
    const int wn = wid & 1;
    const int lr = lane & 15;
    const int lk = (lane >> 4) * 8;

    f32x4 acc[2][4] = {};

    const int sr = t >> 2;
    const int sk = (t & 3) * 16;
    const int aRow = m0 + sr;
    const bool aOk = (aRow < M);
    const int rowSafe = aOk ? aRow : 0;
    const int sw = (sr & 7) << 4;
    const unsigned short* bSrc = Wt + (size_t)(lane >> 3) * 256 + (lane & 7) * 8;

    for (int k0 = 0; k0 < 256; k0 += 64) {
#pragma unroll
        for (int i = 0; i < 2; ++i) {
            const int chunk = i * 8 + wid;
            __builtin_amdgcn_global_load_lds(
                (gvoid*)(bSrc + (size_t)chunk * 8 * 256 + k0),
                (lvoid*)(Bs + chunk * 1024), 16, 0, 0);
        }
        const unsigned short* src =
            (k0 < 128 ? Aa : Ah) + (size_t)rowSafe * 128 + (k0 & 127) + sk;
        const short8 v0 = *(const short8*)(src);
        const short8 v1 = *(const short8*)(src + 8);
        *(short8*)(As + sr * 128 + ((sk * 2) ^ sw)) = v0;
        *(short8*)(As + sr * 128 + ((sk * 2 + 16) ^ sw)) = v1;
        __syncthreads();
#pragma unroll
        for (int ks = 0; ks < 2; ++ks) {
            short8 a[2], b[4];
#pragma unroll
            for (int mf = 0; mf < 2; ++mf) {
                const int r = wm * 32 + mf * 16 + lr;
                a[mf] = *(const short8*)(As + r * 128 + (((ks * 32 + lk) * 2) ^ ((r & 7) << 4)));
            }
#pragma unroll
            for (int nf = 0; nf < 4; ++nf) {
                const int n = wn * 64 + nf * 16 + lr;
                b[nf] = *(const short8*)(Bs + n * 128 + (((ks * 32 + lk) * 2) ^ ((n & 7) << 4)));
            }
#pragma unroll
            for (int mf = 0; mf < 2; ++mf)
#pragma unroll
                for (int nf = 0; nf < 4; ++nf)
                    acc[mf][nf] = __builtin_amdgcn_mfma_f32_16x16x32_bf16(
                        a[mf], b[nf], acc[mf][nf], 0, 0, 0);
        }
        __syncthreads();
    }

#pragma unroll
    for (int mf = 0; mf < 2; ++mf) {
#pragma unroll
        for (int nf = 0; nf < 4; ++nf) {
            const int n = wn * 64 + nf * 16 + lr;
            const float bb = bias[n];
            const f32x4 v = acc[mf][nf];
#pragma unroll
            for (int j = 0; j < 4; ++j) {
                const int m = m0 + wm * 32 + mf * 16 + (lane >> 4) * 4 + j;
                if (m < M) outX[(size_t)m * 128 + n] = f2bf(fmaxf(v[j] + bb, 0.f));
            }
        }
    }
}

// ============ agg1: gather fp8 P -> h (bf16 for GEMM2 + fp8 for agg2) ============
__global__ __launch_bounds__(256) void agg_bias_relu(
    const unsigned char* __restrict__ P8, const unsigned short* __restrict__ Rbf,
    const int* __restrict__ rowptr, const int2* __restrict__ csr,
    unsigned short* __restrict__ hout, unsigned char* __restrict__ h8out, int N)
{
    const int i = blockIdx.x * 16 + (threadIdx.x >> 4);
    const int l = threadIdx.x & 15;
    if (i >= N) return;
    const int beg = rowptr[i];
    const int end = rowptr[i + 1];
    const int c = l * 8;

    float acc0[8] = {}, acc1[8] = {}, acc2[8] = {}, acc3[8] = {};
    int j = beg;
    for (; j + 3 < end; j += 4) {
        const int2 e0 = csr[j],     e1 = csr[j + 1];
        const int2 e2 = csr[j + 2], e3 = csr[j + 3];
        const uint2 u0 = *(const uint2*)(P8 + (size_t)e0.x * 128 + c);
        const uint2 u1 = *(const uint2*)(P8 + (size_t)e1.x * 128 + c);
        const uint2 u2 = *(const uint2*)(P8 + (size_t)e2.x * 128 + c);
        const uint2 u3 = *(const uint2*)(P8 + (size_t)e3.x * 128 + c);
        const float n0 = __builtin_bit_cast(float, e0.y);
        const float n1 = __builtin_bit_cast(float, e1.y);
        const float n2 = __builtin_bit_cast(float, e2.y);
        const float n3 = __builtin_bit_cast(float, e3.y);
        {
            const f32x2 p0 = up8_lo(u0.x), p1 = up8_hi(u0.x);
            const f32x2 p2 = up8_lo(u0.y), p3 = up8_hi(u0.y);
            acc0[0] = fmaf(p0.x, n0, acc0[0]); acc0[1] = fmaf(p0.y, n0, acc0[1]);
            acc0[2] = fmaf(p1.x, n0, acc0[2]); acc0[3] = fmaf(p1.y, n0, acc0[3]);
            acc0[4] = fmaf(p2.x, n0, acc0[4]); acc0[5] = fmaf(p2.y, n0, acc0[5]);
            acc0[6] = fmaf(p3.x, n0, acc0[6]); acc0[7] = fmaf(p3.y, n0, acc0[7]);
        }
        {
            const f32x2 p0 = up8_lo(u1.x), p1 = up8_hi(u1.x);
            const f32x2 p2 = up8_lo(u1.y), p3 = up8_hi(u1.y);
            acc1[0] = fmaf(p0.x, n1, acc1[0]); acc1[1] = fmaf(p0.y, n1, acc1[1]);
            acc1[2] = fmaf(p1.x, n1, acc1[2]); acc1[3] = fmaf(p1.y, n1, acc1[3]);
            acc1[4] = fmaf(p2.x, n1, acc1[4]); acc1[5] = fmaf(p2.y, n1, acc1[5]);
            acc1[6] = fmaf(p3.x, n1, acc1[6]); acc1[7] = fmaf(p3.y, n1, acc1[7]);
        }
        {
            const f32x2 p0 = up8_lo(u2.x), p1 = up8_hi(u2.x);
            const f32x2 p2 = up8_lo(u2.y), p3 = up8_hi(u2.y);
            acc2[0] = fmaf(p0.x, n2, acc2[0]); acc2[1] = fmaf(p0.y, n2, acc2[1]);
            acc2[2] = fmaf(p1.x, n2, acc2[2]); acc2[3] = fmaf(p1.y, n2, acc2[3]);
            acc2[4] = fmaf(p2.x, n2, acc2[4]); acc2[5] = fmaf(p2.y, n2, acc2[5]);
            acc2[6] = fmaf(p3.x, n2, acc2[6]); acc2[7] = fmaf(p3.y, n2, acc2[7]);
        }
        {
            const f32x2 p0 = up8_lo(u3.x), p1 = up8_hi(u3.x);
            const f32x2 p2 = up8_lo(u3.y), p3 = up8_hi(u3.y);
            acc3[0] = fmaf(p0.x, n3, acc3[0]); acc3[1] = fmaf(p0.y, n3, acc3[1]);
            acc3[2] = fmaf(p1.x, n3, acc3[2]); acc3[3] = fmaf(p1.y, n3, acc3[3]);
            acc3[4] = fmaf(p2.x, n3, acc3[4]); acc3[5] = fmaf(p2.y, n3, acc3[5]);
            acc3[6] = fmaf(p3.x, n3, acc3[6]); acc3[7] = fmaf(p3.y, n3, acc3[7]);
        }
    }
    for (; j < end; ++j) {
        const int2 e0 = csr[j];
        const uint2 u0 = *(const uint2*)(P8 + (size_t)e0.x * 128 + c);
        const float n0 = __builtin_bit_cast(float, e0.y);
        const f32x2 p0 = up8_lo(u0.x), p1 = up8_hi(u0.x);
        const f32x2 p2 = up8_lo(u0.y), p3 = up8_hi(u0.y);
        acc0[0] = fmaf(p0.x, n0, acc0[0]); acc0[1] = fmaf(p0.y, n0, acc0[1]);
        acc0[2] = fmaf(p1.x, n0, acc0[2]); acc0[3] = fmaf(p1.y, n0, acc0[3]);
        acc0[4] = fmaf(p2.x, n0, acc0[4]); acc0[5] = fmaf(p2.y, n0, acc0[5]);
        acc0[6] = fmaf(p3.x, n0, acc0[6]); acc0[7] = fmaf(p3.y, n0, acc0[7]);
    }
    const short8 rv = *(const short8*)(Rbf + (size_t)i * 128 + c);
    float s[8];
    short8 ov;
#pragma unroll
    for (int q = 0; q < 8; ++q) {
        s[q] = fmaxf((acc0[q] + acc1[q]) + (acc2[q] + acc3[q]) + b2f(rv[q]), 0.f);
        ov[q] = (short)f2bf(s[q]);
    }
    *(short8*)(hout + (size_t)i * 128 + c) = ov;
    unsigned int w0 = 0, w1 = 0;
    w0 = pk8_lo(s[0], s[1], w0); w0 = pk8_hi(s[2], s[3], w0);
    w1 = pk8_lo(s[4], s[5], w1); w1 = pk8_hi(s[6], s[7], w1);
    uint2 wv = {w0, w1};
    *(uint2*)(h8out + (size_t)i * 128 + c) = wv;
}

// ============ agg2: ah = bf16(gather(fp8 h)) ============
__global__ __launch_bounds__(256) void agg_plain(
    const unsigned char* __restrict__ H8,
    const int* __restrict__ rowptr, const int2* __restrict__ csr,
    unsigned short* __restrict__ ahout, int N)
{
    const int i = blockIdx.x * 16 + (threadIdx.x >> 4);
    const int l = threadIdx.x & 15;
    if (i >= N) return;
    const int beg = rowptr[i];
    const int end = rowptr[i + 1];
    const int c = l * 8;

    float acc0[8] = {}, acc1[8] = {}, acc2[8] = {}, acc3[8] = {};
    int j = beg;
    for (; j + 3 < end; j += 4) {
        const int2 e0 = csr[j],     e1 = csr[j + 1];
        const int2 e2 = csr[j + 2], e3 = csr[j + 3];
        const uint2 u0 = *(const uint2*)(H8 + (size_t)e0.x * 128 + c);
        const uint2 u1 = *(const uint2*)(H8 + (size_t)e1.x * 128 + c);
        const uint2 u2 = *(const uint2*)(H8 + (size_t)e2.x * 128 + c);
        const uint2 u3 = *(const uint2*)(H8 + (size_t)e3.x * 128 + c);
        const float n0 = __builtin_bit_cast(float, e0.y);
        const float n1 = __builtin_bit_cast(float, e1.y);
        const float n2 = __builtin_bit_cast(float, e2.y);
        const float n3 = __builtin_bit_cast(float, e3.y);
        {
            const f32x2 p0 = up8_lo(u0.x), p1 = up8_hi(u0.x);
            const f32x2 p2 = up8_lo(u0.y), p3 = up8_hi(u0.y);
            acc0[0] = fmaf(p0.x, n0, acc0[0]); acc0[1] = fmaf(p0.y, n0, acc0[1]);
            acc0[2] = fmaf(p1.x, n0, acc0[2]); acc0[3] = fmaf(p1.y, n0, acc0[3]);
            acc0[4] = fmaf(p2.x, n0, acc0[4]); acc0[5] = fmaf(p2.y, n0, acc0[5]);
            acc0[6] = fmaf(p3.x, n0, acc0[6]); acc0[7] = fmaf(p3.y, n0, acc0[7]);
        }
        {
            const f32x2 p0 = up8_lo(u1.x), p1 = up8_hi(u1.x);
            const f32x2 p2 = up8_lo(u1.y), p3 = up8_hi(u1.y);
            acc1[0] = fmaf(p0.x, n1, acc1[0]); acc1[1] = fmaf(p0.y, n1, acc1[1]);
            acc1[2] = fmaf(p1.x, n1, acc1[2]); acc1[3] = fmaf(p1.y, n1, acc1[3]);
            acc1[4] = fmaf(p2.x, n1, acc1[4]); acc1[5] = fmaf(p2.y, n1, acc1[5]);
            acc1[6] = fmaf(p3.x, n1, acc1[6]); acc1[7] = fmaf(p3.y, n1, acc1[7]);
        }
        {
            const f32x2 p0 = up8_lo(u2.x), p1 = up8_hi(u2.x);
            const f32x2 p2 = up8_lo(u2.y), p3 = up8_hi(u2.y);
            acc2[0] = fmaf(p0.x, n2, acc2[0]); acc2[1] = fmaf(p0.y, n2, acc2[1]);
            acc2[2] = fmaf(p1.x, n2, acc2[2]); acc2[3] = fmaf(p1.y, n2, acc2[3]);
            acc2[4] = fmaf(p2.x, n2, acc2[4]); acc2[5] = fmaf(p2.y, n2, acc2[5]);
            acc2[6] = fmaf(p3.x, n2, acc2[6]); acc2[7] = fmaf(p3.y, n2, acc2[7]);
        }
        {
            const f32x2 p0 = up8_lo(u3.x), p1 = up8_hi(u3.x);
            const f32x2 p2 = up8_lo(u3.y), p3 = up8_hi(u3.y);
            acc3[0] = fmaf(p0.x, n3, acc3[0]); acc3[1] = fmaf(p0.y, n3, acc3[1]);
            acc3[2] = fmaf(p1.x, n3, acc3[2]); acc3[3] = fmaf(p1.y, n3, acc3[3]);
            acc3[4] = fmaf(p2.x, n3, acc3[4]); acc3[5] = fmaf(p2.y, n3, acc3[5]);
            acc3[6] = fmaf(p3.x, n3, acc3[6]); acc3[7] = fmaf(p3.y, n3, acc3[7]);
        }
    }
    for (; j < end; ++j) {
        const int2 e0 = csr[j];
        const uint2 u0 = *(const uint2*)(H8 + (size_t)e0.x * 128 + c);
        const float n0 = __builtin_bit_cast(float, e0.y);
        const f32x2 p0 = up8_lo(u0.x), p1 = up8_hi(u0.x);
        const f32x2 p2 = up8_lo(u0.y), p3 = up8_hi(u0.y);
        acc0[0] = fmaf(p0.x, n0, acc0[0]); acc0[1] = fmaf(p0.y, n0, acc0[1]);
        acc0[2] = fmaf(p1.x, n0, acc0[2]); acc0[3] = fmaf(p1.y, n0, acc0[3]);
        acc0[4] = fmaf(p2.x, n0, acc0[4]); acc0[5] = fmaf(p2.y, n0, acc0[5]);
        acc0[6] = fmaf(p3.x, n0, acc0[6]); acc0[7] = fmaf(p3.y, n0, acc0[7]);
    }
    short8 ov;
#pragma unroll
    for (int q = 0; q < 8; ++q)
        ov[q] = (short)f2bf((acc0[q] + acc1[q]) + (acc2[q] + acc3[q]));
    *(short8*)(ahout + (size_t)i * 128 + c) = ov;
}

// ============ fused mean-pool (sorted batch, bf16, 4 node-streams) + MLP ============
__global__ __launch_bounds__(256) void pool_mlp(
    const unsigned short* __restrict__ nx, const int* __restrict__ batch, int N,
    const float* __restrict__ Wl1, const float* __restrict__ bl1,
    const float* __restrict__ Wl2, const float* __restrict__ bl2,
    float* __restrict__ out)
{
    __shared__ float gxp[4][128];
    __shared__ float hid[32];
    __shared__ int rng[2];
    const int g = blockIdx.x;
    const int t = threadIdx.x;
    if (t < 2) {
        const int target = g + t;
        int lo = 0, hi = N;
        while (lo < hi) {
            int mid = (lo + hi) >> 1;
            if (batch[mid] < target) lo = mid + 1; else hi = mid;
        }
        rng[t] = lo;
    }
    __syncthreads();
    const int s = rng[0], e = rng[1];
    const int pr = t & 63;
    const int strm = t >> 6;
    float a0 = 0.f, b0 = 0.f, a1 = 0.f, b1 = 0.f;
    int i = s + strm;
    for (; i + 4 < e; i += 8) {
        const unsigned int u = *(const unsigned int*)&nx[(size_t)i * 128 + pr * 2];
        const unsigned int v = *(const unsigned int*)&nx[(size_t)(i + 4) * 128 + pr * 2];
        a0 += b2f((short)(u & 0xffff)); b0 += b2f((short)(u >> 16));
        a1 += b2f((short)(v & 0xffff)); b1 += b2f((short)(v >> 16));
    }
    if (i < e) {
        const unsigned int u = *(const unsigned int*)&nx[(size_t)i * 128 + pr * 2];
        a0 += b2f((short)(u & 0xffff)); b0 += b2f((short)(u >> 16));
    }
    gxp[strm][pr * 2] = a0 + a1;
    gxp[strm][pr * 2 + 1] = b0 + b1;
    __syncthreads();
    if (t < 128) {
        gxp[0][t] = ((gxp[0][t] + gxp[1][t]) + (gxp[2][t] + gxp[3][t]))
                    / fmaxf((float)(e - s), 1.f);
    }
    __syncthreads();
    if (t < 32) {
        float a = bl1[t];
#pragma unroll 8
        for (int k = 0; k < 128; ++k) a = fmaf(gxp[0][k], Wl1[k * 32 + t], a);
        hid[t] = a > 0.f ? a : expm1f(a);
    }
    __syncthreads();
    if (t < 2) {
        float a = bl2[t];
#pragma unroll
        for (int k = 0; k < 32; ++k) a = fmaf(hid[k], Wl2[k * 2 + t], a);
        out[(size_t)g * 2 + t] = a;
    }
}

extern "C" void kernel_launch(void* const* d_in, const int* in_sizes, int n_in,
                              void* d_out, int out_size, void* d_ws, size_t ws_size,
                              hipStream_t stream)
{
    const float* x     = (const float*)d_in[0];
    const int*   ei    = (const int*)d_in[1];
    const float* ea    = (const float*)d_in[2];
    const int*   batch = (const int*)d_in[3];
    const float* W1i   = (const float*)d_in[5];
    const float* W1r   = (const float*)d_in[6];
    const float* b1    = (const float*)d_in[7];
    const float* W2i   = (const float*)d_in[8];
    const float* W2r   = (const float*)d_in[9];
    const float* b2    = (const float*)d_in[10];
    const float* Wl1   = (const float*)d_in[11];
    const float* bl1   = (const float*)d_in[12];
    const float* Wl2   = (const float*)d_in[13];
    const float* bl2   = (const float*)d_in[14];

    const int N = in_sizes[0] / 768;
    const int E = in_sizes[2];
    const int G = out_size / 2;

    char* ws = (char*)d_ws;
    size_t off = 0;
    auto alloc = [&](size_t bytes) -> char* {
        char* p = ws + off;
        off = (off + bytes + 255) & ~(size_t)255;
        return p;
    };
    unsigned long long* packed = (unsigned long long*)alloc((size_t)NC * N * 8);
    int*   rank    = (int*)alloc((size_t)E * 4);
    int*   wpb     = (int*)alloc((size_t)NC * N * 4);
    float* dinv    = (float*)alloc((size_t)N * 4);
    int*   rowptr  = (int*)alloc((size_t)(N + 1) * 4);
    int*   blksum  = (int*)alloc((size_t)256 * 4);
    int2*  csr     = (int2*)alloc((size_t)E * 8);
    unsigned char*  P8   = (unsigned char*)alloc((size_t)N * 128);
    unsigned char*  H8   = (unsigned char*)alloc((size_t)N * 128);
    unsigned short* R1   = (unsigned short*)alloc((size_t)N * 128 * 2);
    unsigned short* hbf  = (unsigned short*)alloc((size_t)N * 128 * 2);
    unsigned short* ahb  = (unsigned short*)alloc((size_t)N * 128 * 2);
    unsigned short* nxb  = (unsigned short*)alloc((size_t)N * 128 * 2);
    unsigned short* W1t  = (unsigned short*)alloc((size_t)256 * 768 * 2);
    unsigned short* W2t  = (unsigned short*)alloc((size_t)128 * 256 * 2);

    const int eBlocks = (E + 255) / 256;
    const int cBlocks = (256 * 768 + 128 * 256 + 255) / 256;
    const int nb      = (N + 1023) / 1024;     // <=256 assumed
    const int nBlocks = (N + 255) / 256;
    const int aBlocks = (N + 15) / 16;

    // ---- CSR build (phases 1-3) + weight convert ----
    (void)hipMemsetAsync(packed, 0, (size_t)NC * N * 8, stream);
    hist_conv_kernel<<<eBlocks + cBlocks, 256, 0, stream>>>(
        ei, ea, packed, rank, N, E, eBlocks, W1i, W1r, W2i, W2r, W1t, W2t);
    scan1p_kernel<<<nb, 256, 0, stream>>>(packed, rowptr, blksum, N);
    scan3_kernel<<<nBlocks, 256, 0, stream>>>(rowptr, blksum, wpb, packed, dinv, N, E, nb);
    place_kernel<<<eBlocks, 256, 0, stream>>>(ei, ea, dinv, wpb, rank, csr, N, E);

    // ---- layer 1: P8 = fp8(x@W1i), R1 = bf16(x@W1r + b1) ----
    gemm_mfma_dual<<<(N + 63) / 64, 512, 0, stream>>>(x, W1t, b1, P8, R1, N, 768);
    // h = relu(R1 + gather(P8)) -> hbf (bf16) + H8 (fp8)
    agg_bias_relu<<<aBlocks, 256, 0, stream>>>(P8, R1, rowptr, csr, hbf, H8, N);

    // ---- layer 2: ah = bf16(gather(H8)); node_x = bf16(relu([ah|h]@W2 + b2)) ----
    agg_plain<<<aBlocks, 256, 0, stream>>>(H8, rowptr, csr, ahb, N);
    gemm_mfma_single<<<(N + 127) / 128, 512, 0, stream>>>(ahb, hbf, W2t, b2, nxb, N);

    // ---- fused pool + head ----
    pool_mlp<<<G, 256, 0, stream>>>(nxb, batch, N, Wl1, bl1, Wl2, bl2, (float*)d_out);
}